// Round 1
// baseline (216.419 us; speedup 1.0000x reference)
//
#include <hip/hip_runtime.h>
#include <hip/hip_bf16.h>

#define SLEN   2048
#define DMODEL 1024
#define NHEADS 16
#define DHEAD  64
#define NBATCH 2
#define EPAD_ROWS 2432   // SLEN + 384 zero rows so rel-band never reads OOB

// Q pre-scale folds softmax 1/8 AND log2(e) so scores are in exp2 domain
#define QSCALE 0.18033688011112042f     // 0.125 * log2(e)
#define EXPB   23.083120654223414f      // 16 * log2(e)

typedef __bf16 bf16x8 __attribute__((ext_vector_type(8)));
typedef float  f32x4  __attribute__((ext_vector_type(4)));

__device__ __forceinline__ unsigned short f2bf(float f) {
    unsigned int u = __builtin_bit_cast(unsigned int, f);
    return (unsigned short)((u + 0x7fffu + ((u >> 16) & 1u)) >> 16);  // RNE
}

// native HW bf16 convert (gfx950: v_cvt bf16; RNE, same as f2bf)
__device__ __forceinline__ unsigned short f2bf_hw(float f) {
    return __builtin_bit_cast(unsigned short, (__bf16)f);
}

__device__ __forceinline__ bf16x8 ld8(const unsigned short* p) {
    union { uint4 u; bf16x8 b; } t;
    t.u = *(const uint4*)p;
    return t.b;
}

// async global->LDS, 16B per lane; lds base must be wave-uniform
__device__ __forceinline__ void glds16(const unsigned short* g, unsigned short* l) {
    __builtin_amdgcn_global_load_lds(
        (const __attribute__((address_space(1))) unsigned int*)g,
        (__attribute__((address_space(3))) unsigned int*)l, 16, 0, 0);
}

// ---------------- merged prep kernel ----------------
// blocks [0,4096): x->bf16 ; [4096,4704): Er pad+cvt ; [4704,7776): W transpose
__global__ __launch_bounds__(256) void prep_kernel(
    const float* __restrict__ x, const float* __restrict__ Er,
    const float* __restrict__ Wq, const float* __restrict__ Wk,
    const float* __restrict__ Wv,
    unsigned short* __restrict__ xb, unsigned short* __restrict__ Ep,
    unsigned short* __restrict__ Wt) {
    const int bi = blockIdx.x, tid = threadIdx.x;
    if (bi < 4096) {
        int i = (bi * 256 + tid) * 4;
        float4 v = *(const float4*)(x + i);
        ushort4 o;
        o.x = f2bf(v.x); o.y = f2bf(v.y); o.z = f2bf(v.z); o.w = f2bf(v.w);
        *(ushort4*)(xb + i) = o;
    } else if (bi < 4704) {
        int i = (bi - 4096) * 256 + tid;        // 2432*64 elements
        int row = i >> 6;
        unsigned short v = 0;
        if (row < SLEN) v = f2bf(Er[i]);
        Ep[i] = v;
    } else {
        __shared__ float tile[32][33];
        const int b3 = bi - 4704;               // 0..3071
        const int z = b3 >> 10, rem = b3 & 1023;
        const int n0 = (rem & 31) * 32, k0 = (rem >> 5) * 32;
        const float* W = (z == 0) ? Wq : (z == 1 ? Wk : Wv);
        unsigned short* out = Wt + (size_t)z * DMODEL * DMODEL;
        const int tx = tid & 31, ty = tid >> 5;  // (32,8)
        for (int r = 0; r < 32; r += 8)
            tile[ty + r][tx] = W[(size_t)(k0 + ty + r) * DMODEL + n0 + tx];
        __syncthreads();
        for (int r = 0; r < 32; r += 8)
            out[(size_t)(n0 + ty + r) * DMODEL + k0 + tx] = f2bf(tile[tx][ty + r]);
    }
}

// ---------------- QKV projection GEMM ---------------------------------------
// 128x128 tile, global_load_lds staging, single-barrier double-buffered
__global__ __launch_bounds__(256) void qkv_gemm(
    const unsigned short* __restrict__ xb, const unsigned short* __restrict__ Wt,
    const float* __restrict__ bq, const float* __restrict__ bk, const float* __restrict__ bv,
    unsigned short* __restrict__ Qs, unsigned short* __restrict__ Ks,
    unsigned short* __restrict__ Vts) {
    const int z = blockIdx.z;
    const float* bias = (z == 0) ? bq : (z == 1 ? bk : bv);
    const unsigned short* Wz = Wt + (size_t)z * DMODEL * DMODEL;
    const int m0 = blockIdx.y * 128, n0 = blockIdx.x * 128;

    __shared__ __align__(16) unsigned short As[2][128][64];
    __shared__ __align__(16) unsigned short Bs[2][128][64];

    const int tid = threadIdx.x;
    const int wave = tid >> 6, lane = tid & 63, l16 = lane & 15, quad = lane >> 4;
    const int wm = (wave >> 1) * 64, wn = (wave & 1) * 64;

    const int lr8 = lane >> 3;
    const int sc  = ((lane & 7) ^ lr8) * 8;    // swizzled source col (u16)

    f32x4 acc[4][4];
#pragma unroll
    for (int mi = 0; mi < 4; mi++)
#pragma unroll
        for (int ni = 0; ni < 4; ni++) acc[mi][ni] = (f32x4){0.f, 0.f, 0.f, 0.f};

    // ---- prologue: stage k0=0 into buf0 ----
#pragma unroll
    for (int c = 0; c < 4; c++) {
        const int seg = wave * 4 + c;
        const int r8  = seg * 8 + lr8;
        glds16(&xb[(size_t)(m0 + r8) * DMODEL + sc], &As[0][seg * 8][0]);
        glds16(&Wz[(size_t)(n0 + r8) * DMODEL + sc], &Bs[0][seg * 8][0]);
    }
    __syncthreads();

    for (int j = 0; j < 16; ++j) {
        const int cur = j & 1;
        // ---- stage k-tile j+1 (covered by compute below) ----
        if (j < 15) {
            const int k1 = (j + 1) * 64, nb = cur ^ 1;
#pragma unroll
            for (int c = 0; c < 4; c++) {
                const int seg = wave * 4 + c;
                const int r8  = seg * 8 + lr8;
                glds16(&xb[(size_t)(m0 + r8) * DMODEL + k1 + sc], &As[nb][seg * 8][0]);
                glds16(&Wz[(size_t)(n0 + r8) * DMODEL + k1 + sc], &Bs[nb][seg * 8][0]);
            }
        }
        // ---- compute k-tile j ----
        const unsigned short (*Aarr)[64] = (z == 2) ? Bs[cur] : As[cur];
        const unsigned short (*Barr)[64] = (z == 2) ? As[cur] : Bs[cur];
#pragma unroll
        for (int ks = 0; ks < 2; ks++) {
            const int pc = ((ks * 4 + quad) ^ (l16 & 7)) * 8;
            bf16x8 a[4], b[4];
#pragma unroll
            for (int mi = 0; mi < 4; mi++) a[mi] = ld8(&Aarr[wm + mi * 16 + l16][pc]);
#pragma unroll
            for (int ni = 0; ni < 4; ni++) b[ni] = ld8(&Barr[wn + ni * 16 + l16][pc]);
#pragma unroll
            for (int mi = 0; mi < 4; mi++)
#pragma unroll
                for (int ni = 0; ni < 4; ni++)
                    acc[mi][ni] = __builtin_amdgcn_mfma_f32_16x16x32_bf16(a[mi], b[ni], acc[mi][ni], 0, 0, 0);
        }
        __syncthreads();   // drains stage(j+1); guards buf reuse
    }

    if (z == 2) {
#pragma unroll
        for (int mi = 0; mi < 4; mi++)
#pragma unroll
            for (int r = 0; r < 4; r++) {
                const int n = n0 + wm + mi * 16 + quad * 4 + r;
                const float bb = bias[n];
                const int h = n >> 6, d = n & 63;
#pragma unroll
                for (int ni = 0; ni < 4; ni++) {
                    const int m = m0 + wn + ni * 16 + l16;
                    const int bi = m >> 11, s = m & 2047;
                    Vts[((size_t)((bi * NHEADS + h) * 64 + d)) * SLEN + s] = f2bf(acc[mi][ni][r] + bb);
                }
            }
    } else {
#pragma unroll
        for (int ni = 0; ni < 4; ni++) {
            const int n = n0 + wn + ni * 16 + l16;
            const float bb = bias[n];
            const int h = n >> 6, d = n & 63;
#pragma unroll
            for (int mi = 0; mi < 4; mi++)
#pragma unroll
                for (int r = 0; r < 4; r++) {
                    const int m = m0 + wm + mi * 16 + quad * 4 + r;
                    const int bi = m >> 11, s = m & 2047;
                    float v = acc[mi][ni][r] + bb;
                    if (z == 0)
                        Qs[((size_t)(bi * NHEADS + h) * SLEN + s) * 64 + d] = f2bf(v * QSCALE);
                    else
                        Ks[((size_t)(bi * NHEADS + h) * SLEN + s) * 64 + d] = f2bf(v);
                }
        }
    }
}

// ---------------- cooperative flash attention, fold-balanced + pipelined ----
// R9 deltas: Er band read straight from global (L2-resident, 311 KB shared by
// all blocks) -> Esh ring + its staging + ring math removed; LDS 75->43 KiB;
// 10 of 28 ds_read_b128/wave-iter moved to the idle VMEM pipe. Er loads are
// issued BEFORE K/V staging so the accE vmcnt wait does not drain the staging
// queue, and QK^T covers their L2 latency. exp() in log2-domain: Q pre-scaled
// by 0.125*log2e, bias -16*log2e folded into accS MFMA init, bare v_exp_f32.
__global__ __launch_bounds__(256, 2) void attn_kernel(
    const unsigned short* __restrict__ Q,   // (BH,S,64), pre-scaled by QSCALE
    const unsigned short* __restrict__ K,   // (BH,S,64)
    const unsigned short* __restrict__ Vt,  // (BH,64,S)
    const unsigned short* __restrict__ Ep,  // (EPAD_ROWS,64) bf16, zero-padded
    float* __restrict__ out) {              // (B,S,DMODEL)
    const int tid = threadIdx.x;
    const int wave = tid >> 6, lane = tid & 63, l16 = lane & 15, quad = lane >> 4;
    const int lr8 = lane >> 3;
    const int swz = ((lane & 7) ^ lr8) * 8;   // swizzled source chunk (u16)

    const int bh = blockIdx.x & 31;
    const int pg = blockIdx.x >> 5;            // 0..15

    __shared__ __align__(16) unsigned short Ksh[2][64 * 64];  // K tile  [t][d], dbuf
    __shared__ __align__(16) unsigned short Vsh[2][64 * 64];  // V^T tile[d][t], dbuf
    __shared__ __align__(16) unsigned short Pg[4][16][88];    // per-wave P (bf16)

    const unsigned short* Qb = Q + (size_t)bh * SLEN * 64;
    const unsigned short* Kb = K + (size_t)bh * SLEN * 64;
    const unsigned short* Vb = Vt + (size_t)bh * 64 * SLEN;
    const int ob = bh >> 4, oh = bh & 15;

    // hoisted loop-invariant lane math
    const int pc0 = (quad ^ (l16 & 7)) * 8;          // de-swizzle, ks=0
    const int pc1 = ((4 + quad) ^ (l16 & 7)) * 8;    // de-swizzle, ks=1
    int perm[4];                                      // skew shuffle lane idx
    bool hi[4];                                       // send-select per r
#pragma unroll
    for (int r = 0; r < 4; r++) {
        const int row16 = quad * 4 + r;
        perm[r] = (quad << 4) | ((l16 + 15 - row16) & 15);
        hi[r] = (l16 + row16 >= 15);
    }

    int s0 = pg * 64;
    int ntp = pg + 1;

#pragma unroll 1
    for (int pass = 0; pass < 2; ++pass) {
        const int sw = s0 + 16 * wave;          // this wave's 16 q-rows
        const bf16x8 aq0 = ld8(Qb + (size_t)(sw + l16) * 64 + quad * 8);
        const bf16x8 aq1 = ld8(Qb + (size_t)(sw + l16) * 64 + 32 + quad * 8);

        f32x4 accO[4];
        float sacc[4];
#pragma unroll
        for (int nt = 0; nt < 4; nt++) accO[nt] = (f32x4){0.f, 0.f, 0.f, 0.f};
#pragma unroll
        for (int r = 0; r < 4; r++) sacc[r] = 0.f;

        // ---- prologue: K/V (t0=0) into buf0 ----
#pragma unroll
        for (int c = 0; c < 2; c++) {
            const int seg = wave * 2 + c;
            glds16(&Kb[(size_t)(seg * 8 + lr8) * 64 + swz], &Ksh[0][seg * 8 * 64]);
            glds16(&Vb[(size_t)(seg * 8 + lr8) * SLEN + swz], &Vsh[0][seg * 8 * 64]);
        }
        __syncthreads();

        for (int j = 0; j < ntp; ++j) {
            const int t0 = j * 64;
            const int cur = j & 1;

            // ---- Er band: straight from global (L2-hit), natural layout.
            // Issued first so later vmcnt waits leave K/V staging in flight.
            const int er0 = SLEN - 16 - sw + t0;   // >= 0 by construction
            bf16x8 be[5][2];
#pragma unroll
            for (int nt = 0; nt < 5; nt++) {
                const unsigned short* ep = Ep + (size_t)(er0 + nt * 16 + l16) * 64 + quad * 8;
                be[nt][0] = ld8(ep);
                be[nt][1] = ld8(ep + 32);
            }

            // ---- prefetch next K/V tile (one full compute phase of cover) ----
            if (j + 1 < ntp) {
                const int t1 = t0 + 64, nb = cur ^ 1;
#pragma unroll
                for (int c = 0; c < 2; c++) {
                    const int seg = wave * 2 + c;
                    glds16(&Kb[(size_t)(t1 + seg * 8 + lr8) * 64 + swz], &Ksh[nb][seg * 8 * 64]);
                    glds16(&Vb[(size_t)(seg * 8 + lr8) * SLEN + t1 + swz], &Vsh[nb][seg * 8 * 64]);
                }
            }

            // ---- QK^T (acc pre-biased with -16*log2e for the exp2 below) ----
            f32x4 accS[4];
#pragma unroll
            for (int nt = 0; nt < 4; nt++)
                accS[nt] = (f32x4){-EXPB, -EXPB, -EXPB, -EXPB};
#pragma unroll
            for (int nt = 0; nt < 4; nt++) {
                bf16x8 bk0 = ld8(&Ksh[cur][(nt * 16 + l16) * 64 + pc0]);
                bf16x8 bk1 = ld8(&Ksh[cur][(nt * 16 + l16) * 64 + pc1]);
                accS[nt] = __builtin_amdgcn_mfma_f32_16x16x32_bf16(aq0, bk0, accS[nt], 0, 0, 0);
                accS[nt] = __builtin_amdgcn_mfma_f32_16x16x32_bf16(aq1, bk1, accS[nt], 0, 0, 0);
            }

            // ---- rel band (80 wide per wave) from registers ----
            f32x4 accE[5];
#pragma unroll
            for (int nt = 0; nt < 5; nt++) accE[nt] = (f32x4){0.f, 0.f, 0.f, 0.f};
#pragma unroll
            for (int nt = 0; nt < 5; nt++) {
                accE[nt] = __builtin_amdgcn_mfma_f32_16x16x32_bf16(aq0, be[nt][0], accE[nt], 0, 0, 0);
                accE[nt] = __builtin_amdgcn_mfma_f32_16x16x32_bf16(aq1, be[nt][1], accE[nt], 0, 0, 0);
            }

            // ---- skew gather + exp2; mask only on the diagonal tile ----
            auto scoreblk = [&](bool masked) {
#pragma unroll
                for (int nt = 0; nt < 4; nt++) {
#pragma unroll
                    for (int r = 0; r < 4; r++) {
                        float send = hi[r] ? accE[nt][r] : accE[nt + 1][r];
                        float rel = __shfl(send, perm[r]);
                        float pexp = __builtin_exp2f(accS[nt][r] + rel);
                        if (masked)
                            pexp = (t0 + nt * 16 + l16 <= sw + quad * 4 + r) ? pexp : 0.0f;
                        sacc[r] += pexp;
                        Pg[wave][quad * 4 + r][nt * 16 + l16] = f2bf_hw(pexp);
                    }
                }
            };
            if (t0 + 63 <= sw) scoreblk(false);   // fully-unmasked tile
            else               scoreblk(true);    // diagonal tile

            // ---- PV (same-wave LDS round trip; no barrier needed) ----
            bf16x8 a0 = ld8(&Pg[wave][l16][quad * 8]);
            bf16x8 a1 = ld8(&Pg[wave][l16][32 + quad * 8]);
#pragma unroll
            for (int nt = 0; nt < 4; nt++) {
                bf16x8 bv0 = ld8(&Vsh[cur][(nt * 16 + l16) * 64 + pc0]);
                bf16x8 bv1 = ld8(&Vsh[cur][(nt * 16 + l16) * 64 + pc1]);
                accO[nt] = __builtin_amdgcn_mfma_f32_16x16x32_bf16(a0, bv0, accO[nt], 0, 0, 0);
                accO[nt] = __builtin_amdgcn_mfma_f32_16x16x32_bf16(a1, bv1, accO[nt], 0, 0, 0);
            }

            __syncthreads();   // staged j+1 landed; compute j done before overwrite
        }

        // ---- pass epilogue: row-sum reduce + normalize + store ----
#pragma unroll
        for (int r = 0; r < 4; r++) {
            float s4 = sacc[r];
#pragma unroll
            for (int off = 1; off < 16; off <<= 1) s4 += __shfl_xor(s4, off);
            const float inv = 1.f / s4;
            const int s = sw + quad * 4 + r;
#pragma unroll
            for (int nt = 0; nt < 4; nt++)
                out[((size_t)(ob * SLEN + s)) * DMODEL + oh * 64 + nt * 16 + l16] =
                    accO[nt][r] * inv;
        }

        // switch to pass B: q-tile 31-pg
        s0 = (31 - pg) * 64;
        ntp = 32 - pg;
    }
}

// ---------------- host launcher ----------------
extern "C" void kernel_launch(void* const* d_in, const int* in_sizes, int n_in,
                              void* d_out, int out_size, void* d_ws, size_t ws_size,
                              hipStream_t stream) {
    const float* x  = (const float*)d_in[0];
    const float* Wq = (const float*)d_in[1];
    const float* bq = (const float*)d_in[2];
    const float* Wk = (const float*)d_in[3];
    const float* bk = (const float*)d_in[4];
    const float* Wv = (const float*)d_in[5];
    const float* bv = (const float*)d_in[6];
    const float* Er = (const float*)d_in[7];
    float* out = (float*)d_out;

    // workspace carve (~38.4 MB total)
    char* p = (char*)d_ws;
    unsigned short* xb  = (unsigned short*)p; p += (size_t)4096 * 1024 * 2;
    unsigned short* Wt  = (unsigned short*)p; p += (size_t)3 * 1024 * 1024 * 2;
    unsigned short* Qs  = (unsigned short*)p; p += (size_t)32 * 2048 * 64 * 2;
    unsigned short* Ks  = (unsigned short*)p; p += (size_t)32 * 2048 * 64 * 2;
    unsigned short* Vts = (unsigned short*)p; p += (size_t)32 * 2048 * 64 * 2;
    unsigned short* Ep  = (unsigned short*)p; p += (size_t)EPAD_ROWS * 64 * 2;

    hipLaunchKernelGGL(prep_kernel, dim3(7776), dim3(256), 0, stream,
                       x, Er, Wq, Wk, Wv, xb, Ep, Wt);
    hipLaunchKernelGGL(qkv_gemm, dim3(8, 32, 3), dim3(256), 0, stream,
                       xb, Wt, bq, bk, bv, Qs, Ks, Vts);
    hipLaunchKernelGGL(attn_kernel, dim3(512), dim3(256), 0, stream, Qs, Ks, Vts, Ep, out);
}

// Round 2
// 180.211 us; speedup vs baseline: 1.2009x; 1.2009x over previous
//
#include <hip/hip_runtime.h>
#include <hip/hip_bf16.h>

#define SLEN   2048
#define DMODEL 1024
#define NHEADS 16
#define DHEAD  64
#define NBATCH 2
#define EPAD_ROWS 2432   // SLEN + 384 zero rows so rel-band/ring never reads OOB

// Q pre-scale folds softmax 1/8 AND log2(e) so scores are in exp2 domain
#define QSCALE 0.18033688011112042f     // 0.125 * log2(e)
#define EXPB   23.083120654223414f      // 16 * log2(e)

typedef __bf16 bf16x8 __attribute__((ext_vector_type(8)));
typedef float  f32x4  __attribute__((ext_vector_type(4)));

__device__ __forceinline__ unsigned short f2bf(float f) {
    unsigned int u = __builtin_bit_cast(unsigned int, f);
    return (unsigned short)((u + 0x7fffu + ((u >> 16) & 1u)) >> 16);  // RNE
}

// native HW bf16 convert (gfx950: v_cvt bf16; RNE, same as f2bf)
__device__ __forceinline__ unsigned short f2bf_hw(float f) {
    return __builtin_bit_cast(unsigned short, (__bf16)f);
}

__device__ __forceinline__ bf16x8 ld8(const unsigned short* p) {
    union { uint4 u; bf16x8 b; } t;
    t.u = *(const uint4*)p;
    return t.b;
}

// async global->LDS, 16B per lane; lds base must be wave-uniform
__device__ __forceinline__ void glds16(const unsigned short* g, unsigned short* l) {
    __builtin_amdgcn_global_load_lds(
        (const __attribute__((address_space(1))) unsigned int*)g,
        (__attribute__((address_space(3))) unsigned int*)l, 16, 0, 0);
}

// ---------------- merged prep kernel ----------------
// blocks [0,4096): x->bf16 ; [4096,4704): Er pad+cvt ; [4704,7776): W transpose
__global__ __launch_bounds__(256) void prep_kernel(
    const float* __restrict__ x, const float* __restrict__ Er,
    const float* __restrict__ Wq, const float* __restrict__ Wk,
    const float* __restrict__ Wv,
    unsigned short* __restrict__ xb, unsigned short* __restrict__ Ep,
    unsigned short* __restrict__ Wt) {
    const int bi = blockIdx.x, tid = threadIdx.x;
    if (bi < 4096) {
        int i = (bi * 256 + tid) * 4;
        float4 v = *(const float4*)(x + i);
        ushort4 o;
        o.x = f2bf(v.x); o.y = f2bf(v.y); o.z = f2bf(v.z); o.w = f2bf(v.w);
        *(ushort4*)(xb + i) = o;
    } else if (bi < 4704) {
        int i = (bi - 4096) * 256 + tid;        // 2432*64 elements
        int row = i >> 6;
        unsigned short v = 0;
        if (row < SLEN) v = f2bf(Er[i]);
        Ep[i] = v;
    } else {
        __shared__ float tile[32][33];
        const int b3 = bi - 4704;               // 0..3071
        const int z = b3 >> 10, rem = b3 & 1023;
        const int n0 = (rem & 31) * 32, k0 = (rem >> 5) * 32;
        const float* W = (z == 0) ? Wq : (z == 1 ? Wk : Wv);
        unsigned short* out = Wt + (size_t)z * DMODEL * DMODEL;
        const int tx = tid & 31, ty = tid >> 5;  // (32,8)
        for (int r = 0; r < 32; r += 8)
            tile[ty + r][tx] = W[(size_t)(k0 + ty + r) * DMODEL + n0 + tx];
        __syncthreads();
        for (int r = 0; r < 32; r += 8)
            out[(size_t)(n0 + ty + r) * DMODEL + k0 + tx] = f2bf(tile[tx][ty + r]);
    }
}

// ---------------- QKV projection GEMM ---------------------------------------
// R10: m97-style single-buffered 128x128 tile. LDS 64KB->32KB so residency
// rises 2->3 blocks/CU and grid 768 = EXACTLY one round of 3x256 (the dbuf
// version ran 1.5 rounds at 2 blocks/CU: ~33% tail idle). Cross-block wave
// overlap hides the staging drain (m114); dbuf adds nothing on top (m99/m100).
__global__ __launch_bounds__(256, 3) void qkv_gemm(
    const unsigned short* __restrict__ xb, const unsigned short* __restrict__ Wt,
    const float* __restrict__ bq, const float* __restrict__ bk, const float* __restrict__ bv,
    unsigned short* __restrict__ Qs, unsigned short* __restrict__ Ks,
    unsigned short* __restrict__ Vts) {
    const int z = blockIdx.z;
    const float* bias = (z == 0) ? bq : (z == 1 ? bk : bv);
    const unsigned short* Wz = Wt + (size_t)z * DMODEL * DMODEL;
    const int m0 = blockIdx.y * 128, n0 = blockIdx.x * 128;

    __shared__ __align__(16) unsigned short As[128][64];
    __shared__ __align__(16) unsigned short Bs[128][64];

    const int tid = threadIdx.x;
    const int wave = tid >> 6, lane = tid & 63, l16 = lane & 15, quad = lane >> 4;
    const int wm = (wave >> 1) * 64, wn = (wave & 1) * 64;

    const int lr8 = lane >> 3;
    const int sc  = ((lane & 7) ^ lr8) * 8;    // swizzled source col (u16)

    f32x4 acc[4][4];
#pragma unroll
    for (int mi = 0; mi < 4; mi++)
#pragma unroll
        for (int ni = 0; ni < 4; ni++) acc[mi][ni] = (f32x4){0.f, 0.f, 0.f, 0.f};

    for (int j = 0; j < 16; ++j) {
        if (j) __syncthreads();                // readers of tile j-1 done
        const int k0 = j * 64;
#pragma unroll
        for (int c = 0; c < 4; c++) {
            const int seg = wave * 4 + c;
            const int r8  = seg * 8 + lr8;
            glds16(&xb[(size_t)(m0 + r8) * DMODEL + k0 + sc], &As[seg * 8][0]);
            glds16(&Wz[(size_t)(n0 + r8) * DMODEL + k0 + sc], &Bs[seg * 8][0]);
        }
        __syncthreads();                       // stage landed (vmcnt drained)

        const unsigned short (*Aarr)[64] = (z == 2) ? Bs : As;
        const unsigned short (*Barr)[64] = (z == 2) ? As : Bs;
#pragma unroll
        for (int ks = 0; ks < 2; ks++) {
            const int pc = ((ks * 4 + quad) ^ (l16 & 7)) * 8;
            bf16x8 a[4], b[4];
#pragma unroll
            for (int mi = 0; mi < 4; mi++) a[mi] = ld8(&Aarr[wm + mi * 16 + l16][pc]);
#pragma unroll
            for (int ni = 0; ni < 4; ni++) b[ni] = ld8(&Barr[wn + ni * 16 + l16][pc]);
#pragma unroll
            for (int mi = 0; mi < 4; mi++)
#pragma unroll
                for (int ni = 0; ni < 4; ni++)
                    acc[mi][ni] = __builtin_amdgcn_mfma_f32_16x16x32_bf16(a[mi], b[ni], acc[mi][ni], 0, 0, 0);
        }
    }

    if (z == 2) {
#pragma unroll
        for (int mi = 0; mi < 4; mi++)
#pragma unroll
            for (int r = 0; r < 4; r++) {
                const int n = n0 + wm + mi * 16 + quad * 4 + r;
                const float bb = bias[n];
                const int h = n >> 6, d = n & 63;
#pragma unroll
                for (int ni = 0; ni < 4; ni++) {
                    const int m = m0 + wn + ni * 16 + l16;
                    const int bi = m >> 11, s = m & 2047;
                    Vts[((size_t)((bi * NHEADS + h) * 64 + d)) * SLEN + s] = f2bf(acc[mi][ni][r] + bb);
                }
            }
    } else {
#pragma unroll
        for (int ni = 0; ni < 4; ni++) {
            const int n = n0 + wn + ni * 16 + l16;
            const float bb = bias[n];
            const int h = n >> 6, d = n & 63;
#pragma unroll
            for (int mi = 0; mi < 4; mi++)
#pragma unroll
                for (int r = 0; r < 4; r++) {
                    const int m = m0 + wm + mi * 16 + quad * 4 + r;
                    const int bi = m >> 11, s = m & 2047;
                    float v = acc[mi][ni][r] + bb;
                    if (z == 0)
                        Qs[((size_t)(bi * NHEADS + h) * SLEN + s) * 64 + d] = f2bf(v * QSCALE);
                    else
                        Ks[((size_t)(bi * NHEADS + h) * SLEN + s) * 64 + d] = f2bf(v);
                }
        }
    }
}

// ---------------- cooperative flash attention, fold-balanced + pipelined ----
// R10: Er back in the LDS ring (R9's global-read variant exposed L2 latency
// per-iteration: compiler sank the loads next to their use to save VGPRs,
// MfmaUtil 16->11, 71->100us). Kept from R9: exp2/log2-domain softmax (Q
// pre-scaled by 0.125*log2e, -16*log2e folded into accS init, bare v_exp_f32).
__global__ __launch_bounds__(256, 2) void attn_kernel(
    const unsigned short* __restrict__ Q,   // (BH,S,64), pre-scaled by QSCALE
    const unsigned short* __restrict__ K,   // (BH,S,64)
    const unsigned short* __restrict__ Vt,  // (BH,64,S)
    const unsigned short* __restrict__ Ep,  // (EPAD_ROWS,64)
    float* __restrict__ out) {              // (B,S,DMODEL)
    const int tid = threadIdx.x;
    const int wave = tid >> 6, lane = tid & 63, l16 = lane & 15, quad = lane >> 4;
    const int lr8 = lane >> 3;
    const int swz = ((lane & 7) ^ lr8) * 8;   // swizzled source chunk (u16)

    const int bh = blockIdx.x & 31;
    const int pg = blockIdx.x >> 5;            // 0..15

    __shared__ __align__(16) unsigned short Ksh[2][64 * 64];  // K tile  [t][d], dbuf
    __shared__ __align__(16) unsigned short Vsh[2][64 * 64];  // V^T tile[d][t], dbuf
    __shared__ __align__(16) unsigned short Esh[256 * 64];    // Er ring (4 panels)
    __shared__ __align__(16) unsigned short Pg[4][16][88];    // per-wave P (bf16)

    const unsigned short* Qb = Q + (size_t)bh * SLEN * 64;
    const unsigned short* Kb = K + (size_t)bh * SLEN * 64;
    const unsigned short* Vb = Vt + (size_t)bh * 64 * SLEN;
    const int ob = bh >> 4, oh = bh & 15;

    // hoisted loop-invariant lane math
    const int pc0 = (quad ^ (l16 & 7)) * 8;          // de-swizzle, ks=0
    const int pc1 = ((4 + quad) ^ (l16 & 7)) * 8;    // de-swizzle, ks=1
    int perm[4];                                      // skew shuffle lane idx
    bool hi[4];                                       // send-select per r
#pragma unroll
    for (int r = 0; r < 4; r++) {
        const int row16 = quad * 4 + r;
        perm[r] = (quad << 4) | ((l16 + 15 - row16) & 15);
        hi[r] = (l16 + row16 >= 15);
    }

    int s0 = pg * 64;
    int ntp = pg + 1;

#pragma unroll 1
    for (int pass = 0; pass < 2; ++pass) {
        const int sw = s0 + 16 * wave;          // this wave's 16 q-rows
        const bf16x8 aq0 = ld8(Qb + (size_t)(sw + l16) * 64 + quad * 8);
        const bf16x8 aq1 = ld8(Qb + (size_t)(sw + l16) * 64 + 32 + quad * 8);

        f32x4 accO[4];
        float sacc[4];
#pragma unroll
        for (int nt = 0; nt < 4; nt++) accO[nt] = (f32x4){0.f, 0.f, 0.f, 0.f};
#pragma unroll
        for (int r = 0; r < 4; r++) sacc[r] = 0.f;

        const int p0row = SLEN - 64 - s0;       // Er panel base at t0=0 (mult of 64)

        // ---- prologue: K/V (t0=0) into buf0 + Er panels p0row..p0row+191 ----
#pragma unroll
        for (int c = 0; c < 2; c++) {
            const int seg = wave * 2 + c;
            glds16(&Kb[(size_t)(seg * 8 + lr8) * 64 + swz], &Ksh[0][seg * 8 * 64]);
            glds16(&Vb[(size_t)(seg * 8 + lr8) * SLEN + swz], &Vsh[0][seg * 8 * 64]);
        }
#pragma unroll
        for (int u = 0; u < 6; u++) {
            const int idx = wave * 6 + u;       // 24 segs = 3 panels (192 rows)
            const int grow = p0row + idx * 8;
            glds16(&Ep[(size_t)(grow + lr8) * 64 + swz], &Esh[(grow & 255) * 64]);
        }
        __syncthreads();

        for (int j = 0; j < ntp; ++j) {
            const int t0 = j * 64;
            const int cur = j & 1;

            // ---- prefetch next tile (one full compute phase of cover) ----
            if (j + 1 < ntp) {
                const int t1 = t0 + 64, nb = cur ^ 1;
#pragma unroll
                for (int c = 0; c < 2; c++) {
                    const int seg = wave * 2 + c;
                    glds16(&Kb[(size_t)(t1 + seg * 8 + lr8) * 64 + swz], &Ksh[nb][seg * 8 * 64]);
                    glds16(&Vb[(size_t)(seg * 8 + lr8) * SLEN + t1 + swz], &Vsh[nb][seg * 8 * 64]);
                }
                const int er = p0row + t0 + 128;  // panel needed at iter j+1
#pragma unroll
                for (int c = 0; c < 2; c++) {
                    const int seg = wave * 2 + c;
                    glds16(&Ep[(size_t)(er + seg * 8 + lr8) * 64 + swz],
                           &Esh[((er + seg * 8) & 255) * 64]);
                }
            }

            // ---- QK^T (acc pre-biased with -16*log2e for the exp2 below) ----
            f32x4 accS[4];
#pragma unroll
            for (int nt = 0; nt < 4; nt++)
                accS[nt] = (f32x4){-EXPB, -EXPB, -EXPB, -EXPB};
#pragma unroll
            for (int nt = 0; nt < 4; nt++) {
                bf16x8 bk0 = ld8(&Ksh[cur][(nt * 16 + l16) * 64 + pc0]);
                bf16x8 bk1 = ld8(&Ksh[cur][(nt * 16 + l16) * 64 + pc1]);
                accS[nt] = __builtin_amdgcn_mfma_f32_16x16x32_bf16(aq0, bk0, accS[nt], 0, 0, 0);
                accS[nt] = __builtin_amdgcn_mfma_f32_16x16x32_bf16(aq1, bk1, accS[nt], 0, 0, 0);
            }

            // ---- rel band from 256-row Er ring (80 wide per wave) ----
            const int rm0 = (SLEN - 16 - sw + t0) & 255;
            f32x4 accE[5];
#pragma unroll
            for (int nt = 0; nt < 5; nt++) accE[nt] = (f32x4){0.f, 0.f, 0.f, 0.f};
#pragma unroll
            for (int nt = 0; nt < 5; nt++) {
                const int rowm = (rm0 + nt * 16 + l16) & 255;
                bf16x8 be0 = ld8(&Esh[rowm * 64 + pc0]);
                bf16x8 be1 = ld8(&Esh[rowm * 64 + pc1]);
                accE[nt] = __builtin_amdgcn_mfma_f32_16x16x32_bf16(aq0, be0, accE[nt], 0, 0, 0);
                accE[nt] = __builtin_amdgcn_mfma_f32_16x16x32_bf16(aq1, be1, accE[nt], 0, 0, 0);
            }

            // ---- skew gather + exp2; mask only on the diagonal tile ----
            auto scoreblk = [&](bool masked) {
#pragma unroll
                for (int nt = 0; nt < 4; nt++) {
#pragma unroll
                    for (int r = 0; r < 4; r++) {
                        float send = hi[r] ? accE[nt][r] : accE[nt + 1][r];
                        float rel = __shfl(send, perm[r]);
                        float pexp = __builtin_exp2f(accS[nt][r] + rel);
                        if (masked)
                            pexp = (t0 + nt * 16 + l16 <= sw + quad * 4 + r) ? pexp : 0.0f;
                        sacc[r] += pexp;
                        Pg[wave][quad * 4 + r][nt * 16 + l16] = f2bf_hw(pexp);
                    }
                }
            };
            if (t0 + 63 <= sw) scoreblk(false);   // fully-unmasked tile
            else               scoreblk(true);    // diagonal tile

            // ---- PV (same-wave LDS round trip; no barrier needed) ----
            bf16x8 a0 = ld8(&Pg[wave][l16][quad * 8]);
            bf16x8 a1 = ld8(&Pg[wave][l16][32 + quad * 8]);
#pragma unroll
            for (int nt = 0; nt < 4; nt++) {
                bf16x8 bv0 = ld8(&Vsh[cur][(nt * 16 + l16) * 64 + pc0]);
                bf16x8 bv1 = ld8(&Vsh[cur][(nt * 16 + l16) * 64 + pc1]);
                accO[nt] = __builtin_amdgcn_mfma_f32_16x16x32_bf16(a0, bv0, accO[nt], 0, 0, 0);
                accO[nt] = __builtin_amdgcn_mfma_f32_16x16x32_bf16(a1, bv1, accO[nt], 0, 0, 0);
            }

            __syncthreads();   // staged j+1 landed; compute j done before overwrite
        }

        // ---- pass epilogue: row-sum reduce + normalize + store ----
#pragma unroll
        for (int r = 0; r < 4; r++) {
            float s4 = sacc[r];
#pragma unroll
            for (int off = 1; off < 16; off <<= 1) s4 += __shfl_xor(s4, off);
            const float inv = 1.f / s4;
            const int s = sw + quad * 4 + r;
#pragma unroll
            for (int nt = 0; nt < 4; nt++)
                out[((size_t)(ob * SLEN + s)) * DMODEL + oh * 64 + nt * 16 + l16] =
                    accO[nt][r] * inv;
        }

        // switch to pass B: q-tile 31-pg
        s0 = (31 - pg) * 64;
        ntp = 32 - pg;
    }
}

// ---------------- host launcher ----------------
extern "C" void kernel_launch(void* const* d_in, const int* in_sizes, int n_in,
                              void* d_out, int out_size, void* d_ws, size_t ws_size,
                              hipStream_t stream) {
    const float* x  = (const float*)d_in[0];
    const float* Wq = (const float*)d_in[1];
    const float* bq = (const float*)d_in[2];
    const float* Wk = (const float*)d_in[3];
    const float* bk = (const float*)d_in[4];
    const float* Wv = (const float*)d_in[5];
    const float* bv = (const float*)d_in[6];
    const float* Er = (const float*)d_in[7];
    float* out = (float*)d_out;

    // workspace carve (~38.4 MB total)
    char* p = (char*)d_ws;
    unsigned short* xb  = (unsigned short*)p; p += (size_t)4096 * 1024 * 2;
    unsigned short* Wt  = (unsigned short*)p; p += (size_t)3 * 1024 * 1024 * 2;
    unsigned short* Qs  = (unsigned short*)p; p += (size_t)32 * 2048 * 64 * 2;
    unsigned short* Ks  = (unsigned short*)p; p += (size_t)32 * 2048 * 64 * 2;
    unsigned short* Vts = (unsigned short*)p; p += (size_t)32 * 2048 * 64 * 2;
    unsigned short* Ep  = (unsigned short*)p; p += (size_t)EPAD_ROWS * 64 * 2;

    hipLaunchKernelGGL(prep_kernel, dim3(7776), dim3(256), 0, stream,
                       x, Er, Wq, Wk, Wv, xb, Ep, Wt);
    hipLaunchKernelGGL(qkv_gemm, dim3(8, 32, 3), dim3(256), 0, stream,
                       xb, Wt, bq, bk, bv, Qs, Ks, Vts);
    hipLaunchKernelGGL(attn_kernel, dim3(512), dim3(256), 0, stream, Qs, Ks, Vts, Ep, out);
}

// Round 3
// 177.450 us; speedup vs baseline: 1.2196x; 1.0156x over previous
//
#include <hip/hip_runtime.h>
#include <hip/hip_bf16.h>

#define SLEN   2048
#define DMODEL 1024
#define NHEADS 16
#define DHEAD  64
#define NBATCH 2
#define EPAD_ROWS 2432   // SLEN + 384 zero rows so rel-band/ring never reads OOB

// Q pre-scale folds softmax 1/8 AND log2(e) so scores are in exp2 domain
#define QSCALE 0.18033688011112042f     // 0.125 * log2(e)
#define EXPB   23.083120654223414f      // 16 * log2(e)

typedef __bf16 bf16x8 __attribute__((ext_vector_type(8)));
typedef float  f32x4  __attribute__((ext_vector_type(4)));

__device__ __forceinline__ unsigned short f2bf(float f) {
    unsigned int u = __builtin_bit_cast(unsigned int, f);
    return (unsigned short)((u + 0x7fffu + ((u >> 16) & 1u)) >> 16);  // RNE
}

// native HW bf16 convert (gfx950: v_cvt bf16; RNE, same as f2bf)
__device__ __forceinline__ unsigned short f2bf_hw(float f) {
    return __builtin_bit_cast(unsigned short, (__bf16)f);
}

// bare v_exp_f32 (2^x). __builtin_exp2f without fast-math can lower to the
// guarded __ocml_exp2_f32 (denorm/range branches) — suspected cause of the
// R2 VALUBusy rise. Args here are in [-60, 20]: flush-to-zero is fine.
__device__ __forceinline__ float exp2_hw(float x) {
    float r;
    asm("v_exp_f32 %0, %1" : "=v"(r) : "v"(x));
    return r;
}

__device__ __forceinline__ bf16x8 ld8(const unsigned short* p) {
    union { uint4 u; bf16x8 b; } t;
    t.u = *(const uint4*)p;
    return t.b;
}

// async global->LDS, 16B per lane; lds base must be wave-uniform
__device__ __forceinline__ void glds16(const unsigned short* g, unsigned short* l) {
    __builtin_amdgcn_global_load_lds(
        (const __attribute__((address_space(1))) unsigned int*)g,
        (__attribute__((address_space(3))) unsigned int*)l, 16, 0, 0);
}

// ---------------- merged prep kernel ----------------
// blocks [0,4096): x->bf16 ; [4096,4704): Er pad+cvt ; [4704,7776): W transpose
__global__ __launch_bounds__(256) void prep_kernel(
    const float* __restrict__ x, const float* __restrict__ Er,
    const float* __restrict__ Wq, const float* __restrict__ Wk,
    const float* __restrict__ Wv,
    unsigned short* __restrict__ xb, unsigned short* __restrict__ Ep,
    unsigned short* __restrict__ Wt) {
    const int bi = blockIdx.x, tid = threadIdx.x;
    if (bi < 4096) {
        int i = (bi * 256 + tid) * 4;
        float4 v = *(const float4*)(x + i);
        ushort4 o;
        o.x = f2bf(v.x); o.y = f2bf(v.y); o.z = f2bf(v.z); o.w = f2bf(v.w);
        *(ushort4*)(xb + i) = o;
    } else if (bi < 4704) {
        int i = (bi - 4096) * 256 + tid;        // 2432*64 elements
        int row = i >> 6;
        unsigned short v = 0;
        if (row < SLEN) v = f2bf(Er[i]);
        Ep[i] = v;
    } else {
        __shared__ float tile[32][33];
        const int b3 = bi - 4704;               // 0..3071
        const int z = b3 >> 10, rem = b3 & 1023;
        const int n0 = (rem & 31) * 32, k0 = (rem >> 5) * 32;
        const float* W = (z == 0) ? Wq : (z == 1 ? Wk : Wv);
        unsigned short* out = Wt + (size_t)z * DMODEL * DMODEL;
        const int tx = tid & 31, ty = tid >> 5;  // (32,8)
        for (int r = 0; r < 32; r += 8)
            tile[ty + r][tx] = W[(size_t)(k0 + ty + r) * DMODEL + n0 + tx];
        __syncthreads();
        for (int r = 0; r < 32; r += 8)
            out[(size_t)(n0 + ty + r) * DMODEL + k0 + tx] = f2bf(tile[tx][ty + r]);
    }
}

// ---------------- QKV projection GEMM ---------------------------------------
// R10: m97-style single-buffered 128x128 tile, 3 blocks/CU, one full round.
// R11: XCD-brick blockIdx remap. Default (8,32,3) grid round-robins the 8
// XCDs, so blocks sharing A-panels (8 n-tiles) and B-panels (32 m-tiles) sit
// on DIFFERENT per-XCD L2s; xb(8MB)/Wt(6MB) fit no single 4MB L2 -> ~250MB of
// L3 re-fetch (invisible in FETCH_SIZE, which is HBM-only). Remap: XCD x
// (= blockIdx&7 under round-robin dispatch) gets an 8m x 4n x 3z brick = its
// exactly-co-resident 96 blocks (32 CU x 3 blocks); working set ~5MB/XCD.
__global__ __launch_bounds__(256, 3) void qkv_gemm(
    const unsigned short* __restrict__ xb, const unsigned short* __restrict__ Wt,
    const float* __restrict__ bq, const float* __restrict__ bk, const float* __restrict__ bv,
    unsigned short* __restrict__ Qs, unsigned short* __restrict__ Ks,
    unsigned short* __restrict__ Vts) {
    const int b = blockIdx.x;
    const int x7 = b & 7, s = b >> 3;
    const int mt = ((x7 >> 1) << 3) | (s & 7);        // 0..31
    const int ntile = ((x7 & 1) << 2) | ((s >> 3) & 3); // 0..7
    const int z = s >> 5;                               // 0..2
    const int m0 = mt * 128, n0 = ntile * 128;

    const float* bias = (z == 0) ? bq : (z == 1 ? bk : bv);
    const unsigned short* Wz = Wt + (size_t)z * DMODEL * DMODEL;

    __shared__ __align__(16) unsigned short As[128][64];
    __shared__ __align__(16) unsigned short Bs[128][64];

    const int tid = threadIdx.x;
    const int wave = tid >> 6, lane = tid & 63, l16 = lane & 15, quad = lane >> 4;
    const int wm = (wave >> 1) * 64, wn = (wave & 1) * 64;

    const int lr8 = lane >> 3;
    const int sc  = ((lane & 7) ^ lr8) * 8;    // swizzled source col (u16)

    f32x4 acc[4][4];
#pragma unroll
    for (int mi = 0; mi < 4; mi++)
#pragma unroll
        for (int ni = 0; ni < 4; ni++) acc[mi][ni] = (f32x4){0.f, 0.f, 0.f, 0.f};

    for (int j = 0; j < 16; ++j) {
        if (j) __syncthreads();                // readers of tile j-1 done
        const int k0 = j * 64;
#pragma unroll
        for (int c = 0; c < 4; c++) {
            const int seg = wave * 4 + c;
            const int r8  = seg * 8 + lr8;
            glds16(&xb[(size_t)(m0 + r8) * DMODEL + k0 + sc], &As[seg * 8][0]);
            glds16(&Wz[(size_t)(n0 + r8) * DMODEL + k0 + sc], &Bs[seg * 8][0]);
        }
        __syncthreads();                       // stage landed (vmcnt drained)

        const unsigned short (*Aarr)[64] = (z == 2) ? Bs : As;
        const unsigned short (*Barr)[64] = (z == 2) ? As : Bs;
#pragma unroll
        for (int ks = 0; ks < 2; ks++) {
            const int pc = ((ks * 4 + quad) ^ (l16 & 7)) * 8;
            bf16x8 a[4], bb[4];
#pragma unroll
            for (int mi = 0; mi < 4; mi++) a[mi] = ld8(&Aarr[wm + mi * 16 + l16][pc]);
#pragma unroll
            for (int ni = 0; ni < 4; ni++) bb[ni] = ld8(&Barr[wn + ni * 16 + l16][pc]);
#pragma unroll
            for (int mi = 0; mi < 4; mi++)
#pragma unroll
                for (int ni = 0; ni < 4; ni++)
                    acc[mi][ni] = __builtin_amdgcn_mfma_f32_16x16x32_bf16(a[mi], bb[ni], acc[mi][ni], 0, 0, 0);
        }
    }

    if (z == 2) {
#pragma unroll
        for (int mi = 0; mi < 4; mi++)
#pragma unroll
            for (int r = 0; r < 4; r++) {
                const int n = n0 + wm + mi * 16 + quad * 4 + r;
                const float bb = bias[n];
                const int h = n >> 6, d = n & 63;
#pragma unroll
                for (int ni = 0; ni < 4; ni++) {
                    const int m = m0 + wn + ni * 16 + l16;
                    const int bi = m >> 11, ss = m & 2047;
                    Vts[((size_t)((bi * NHEADS + h) * 64 + d)) * SLEN + ss] = f2bf(acc[mi][ni][r] + bb);
                }
            }
    } else {
#pragma unroll
        for (int ni = 0; ni < 4; ni++) {
            const int n = n0 + wn + ni * 16 + l16;
            const float bb = bias[n];
            const int h = n >> 6, d = n & 63;
#pragma unroll
            for (int mi = 0; mi < 4; mi++)
#pragma unroll
                for (int r = 0; r < 4; r++) {
                    const int m = m0 + wm + mi * 16 + quad * 4 + r;
                    const int bi = m >> 11, ss = m & 2047;
                    float v = acc[mi][ni][r] + bb;
                    if (z == 0)
                        Qs[((size_t)(bi * NHEADS + h) * SLEN + ss) * 64 + d] = f2bf(v * QSCALE);
                    else
                        Ks[((size_t)(bi * NHEADS + h) * SLEN + ss) * 64 + d] = f2bf(v);
                }
        }
    }
}

// ---------------- cooperative flash attention, fold-balanced + pipelined ----
// R11: exp via bare v_exp_f32 inline asm (suspect __builtin_exp2f lowered to
// guarded __ocml_exp2_f32 in R2: VALUBusy 36->40.7 at identical LDS/FETCH).
// Structure identical to the 71.4us R0 kernel otherwise.
__global__ __launch_bounds__(256, 2) void attn_kernel(
    const unsigned short* __restrict__ Q,   // (BH,S,64), pre-scaled by QSCALE
    const unsigned short* __restrict__ K,   // (BH,S,64)
    const unsigned short* __restrict__ Vt,  // (BH,64,S)
    const unsigned short* __restrict__ Ep,  // (EPAD_ROWS,64)
    float* __restrict__ out) {              // (B,S,DMODEL)
    const int tid = threadIdx.x;
    const int wave = tid >> 6, lane = tid & 63, l16 = lane & 15, quad = lane >> 4;
    const int lr8 = lane >> 3;
    const int swz = ((lane & 7) ^ lr8) * 8;   // swizzled source chunk (u16)

    const int bh = blockIdx.x & 31;
    const int pg = blockIdx.x >> 5;            // 0..15

    __shared__ __align__(16) unsigned short Ksh[2][64 * 64];  // K tile  [t][d], dbuf
    __shared__ __align__(16) unsigned short Vsh[2][64 * 64];  // V^T tile[d][t], dbuf
    __shared__ __align__(16) unsigned short Esh[256 * 64];    // Er ring (4 panels)
    __shared__ __align__(16) unsigned short Pg[4][16][88];    // per-wave P (bf16)

    const unsigned short* Qb = Q + (size_t)bh * SLEN * 64;
    const unsigned short* Kb = K + (size_t)bh * SLEN * 64;
    const unsigned short* Vb = Vt + (size_t)bh * 64 * SLEN;
    const int ob = bh >> 4, oh = bh & 15;

    // hoisted loop-invariant lane math
    const int pc0 = (quad ^ (l16 & 7)) * 8;          // de-swizzle, ks=0
    const int pc1 = ((4 + quad) ^ (l16 & 7)) * 8;    // de-swizzle, ks=1
    int perm[4];                                      // skew shuffle lane idx
    bool hi[4];                                       // send-select per r
#pragma unroll
    for (int r = 0; r < 4; r++) {
        const int row16 = quad * 4 + r;
        perm[r] = (quad << 4) | ((l16 + 15 - row16) & 15);
        hi[r] = (l16 + row16 >= 15);
    }

    int s0 = pg * 64;
    int ntp = pg + 1;

#pragma unroll 1
    for (int pass = 0; pass < 2; ++pass) {
        const int sw = s0 + 16 * wave;          // this wave's 16 q-rows
        const bf16x8 aq0 = ld8(Qb + (size_t)(sw + l16) * 64 + quad * 8);
        const bf16x8 aq1 = ld8(Qb + (size_t)(sw + l16) * 64 + 32 + quad * 8);

        f32x4 accO[4];
        float sacc[4];
#pragma unroll
        for (int nt = 0; nt < 4; nt++) accO[nt] = (f32x4){0.f, 0.f, 0.f, 0.f};
#pragma unroll
        for (int r = 0; r < 4; r++) sacc[r] = 0.f;

        const int p0row = SLEN - 64 - s0;       // Er panel base at t0=0 (mult of 64)

        // ---- prologue: K/V (t0=0) into buf0 + Er panels p0row..p0row+191 ----
#pragma unroll
        for (int c = 0; c < 2; c++) {
            const int seg = wave * 2 + c;
            glds16(&Kb[(size_t)(seg * 8 + lr8) * 64 + swz], &Ksh[0][seg * 8 * 64]);
            glds16(&Vb[(size_t)(seg * 8 + lr8) * SLEN + swz], &Vsh[0][seg * 8 * 64]);
        }
#pragma unroll
        for (int u = 0; u < 6; u++) {
            const int idx = wave * 6 + u;       // 24 segs = 3 panels (192 rows)
            const int grow = p0row + idx * 8;
            glds16(&Ep[(size_t)(grow + lr8) * 64 + swz], &Esh[(grow & 255) * 64]);
        }
        __syncthreads();

        for (int j = 0; j < ntp; ++j) {
            const int t0 = j * 64;
            const int cur = j & 1;

            // ---- prefetch next tile (one full compute phase of cover) ----
            if (j + 1 < ntp) {
                const int t1 = t0 + 64, nb = cur ^ 1;
#pragma unroll
                for (int c = 0; c < 2; c++) {
                    const int seg = wave * 2 + c;
                    glds16(&Kb[(size_t)(t1 + seg * 8 + lr8) * 64 + swz], &Ksh[nb][seg * 8 * 64]);
                    glds16(&Vb[(size_t)(seg * 8 + lr8) * SLEN + t1 + swz], &Vsh[nb][seg * 8 * 64]);
                }
                const int er = p0row + t0 + 128;  // panel needed at iter j+1
#pragma unroll
                for (int c = 0; c < 2; c++) {
                    const int seg = wave * 2 + c;
                    glds16(&Ep[(size_t)(er + seg * 8 + lr8) * 64 + swz],
                           &Esh[((er + seg * 8) & 255) * 64]);
                }
            }

            // ---- QK^T (acc pre-biased with -16*log2e for the exp2 below) ----
            f32x4 accS[4];
#pragma unroll
            for (int nt = 0; nt < 4; nt++)
                accS[nt] = (f32x4){-EXPB, -EXPB, -EXPB, -EXPB};
#pragma unroll
            for (int nt = 0; nt < 4; nt++) {
                bf16x8 bk0 = ld8(&Ksh[cur][(nt * 16 + l16) * 64 + pc0]);
                bf16x8 bk1 = ld8(&Ksh[cur][(nt * 16 + l16) * 64 + pc1]);
                accS[nt] = __builtin_amdgcn_mfma_f32_16x16x32_bf16(aq0, bk0, accS[nt], 0, 0, 0);
                accS[nt] = __builtin_amdgcn_mfma_f32_16x16x32_bf16(aq1, bk1, accS[nt], 0, 0, 0);
            }

            // ---- rel band from 256-row Er ring (80 wide per wave) ----
            const int rm0 = (SLEN - 16 - sw + t0) & 255;
            f32x4 accE[5];
#pragma unroll
            for (int nt = 0; nt < 5; nt++) accE[nt] = (f32x4){0.f, 0.f, 0.f, 0.f};
#pragma unroll
            for (int nt = 0; nt < 5; nt++) {
                const int rowm = (rm0 + nt * 16 + l16) & 255;
                bf16x8 be0 = ld8(&Esh[rowm * 64 + pc0]);
                bf16x8 be1 = ld8(&Esh[rowm * 64 + pc1]);
                accE[nt] = __builtin_amdgcn_mfma_f32_16x16x32_bf16(aq0, be0, accE[nt], 0, 0, 0);
                accE[nt] = __builtin_amdgcn_mfma_f32_16x16x32_bf16(aq1, be1, accE[nt], 0, 0, 0);
            }

            // ---- skew gather + exp2; mask only on the diagonal tile ----
            auto scoreblk = [&](bool masked) {
#pragma unroll
                for (int nt = 0; nt < 4; nt++) {
#pragma unroll
                    for (int r = 0; r < 4; r++) {
                        float send = hi[r] ? accE[nt][r] : accE[nt + 1][r];
                        float rel = __shfl(send, perm[r]);
                        float pexp = exp2_hw(accS[nt][r] + rel);
                        if (masked)
                            pexp = (t0 + nt * 16 + l16 <= sw + quad * 4 + r) ? pexp : 0.0f;
                        sacc[r] += pexp;
                        Pg[wave][quad * 4 + r][nt * 16 + l16] = f2bf_hw(pexp);
                    }
                }
            };
            if (t0 + 63 <= sw) scoreblk(false);   // fully-unmasked tile
            else               scoreblk(true);    // diagonal tile

            // ---- PV (same-wave LDS round trip; no barrier needed) ----
            bf16x8 a0 = ld8(&Pg[wave][l16][quad * 8]);
            bf16x8 a1 = ld8(&Pg[wave][l16][32 + quad * 8]);
#pragma unroll
            for (int nt = 0; nt < 4; nt++) {
                bf16x8 bv0 = ld8(&Vsh[cur][(nt * 16 + l16) * 64 + pc0]);
                bf16x8 bv1 = ld8(&Vsh[cur][(nt * 16 + l16) * 64 + pc1]);
                accO[nt] = __builtin_amdgcn_mfma_f32_16x16x32_bf16(a0, bv0, accO[nt], 0, 0, 0);
                accO[nt] = __builtin_amdgcn_mfma_f32_16x16x32_bf16(a1, bv1, accO[nt], 0, 0, 0);
            }

            __syncthreads();   // staged j+1 landed; compute j done before overwrite
        }

        // ---- pass epilogue: row-sum reduce + normalize + store ----
#pragma unroll
        for (int r = 0; r < 4; r++) {
            float s4 = sacc[r];
#pragma unroll
            for (int off = 1; off < 16; off <<= 1) s4 += __shfl_xor(s4, off);
            const float inv = 1.f / s4;
            const int s = sw + quad * 4 + r;
#pragma unroll
            for (int nt = 0; nt < 4; nt++)
                out[((size_t)(ob * SLEN + s)) * DMODEL + oh * 64 + nt * 16 + l16] =
                    accO[nt][r] * inv;
        }

        // switch to pass B: q-tile 31-pg
        s0 = (31 - pg) * 64;
        ntp = 32 - pg;
    }
}

// ---------------- host launcher ----------------
extern "C" void kernel_launch(void* const* d_in, const int* in_sizes, int n_in,
                              void* d_out, int out_size, void* d_ws, size_t ws_size,
                              hipStream_t stream) {
    const float* x  = (const float*)d_in[0];
    const float* Wq = (const float*)d_in[1];
    const float* bq = (const float*)d_in[2];
    const float* Wk = (const float*)d_in[3];
    const float* bk = (const float*)d_in[4];
    const float* Wv = (const float*)d_in[5];
    const float* bv = (const float*)d_in[6];
    const float* Er = (const float*)d_in[7];
    float* out = (float*)d_out;

    // workspace carve (~38.4 MB total)
    char* p = (char*)d_ws;
    unsigned short* xb  = (unsigned short*)p; p += (size_t)4096 * 1024 * 2;
    unsigned short* Wt  = (unsigned short*)p; p += (size_t)3 * 1024 * 1024 * 2;
    unsigned short* Qs  = (unsigned short*)p; p += (size_t)32 * 2048 * 64 * 2;
    unsigned short* Ks  = (unsigned short*)p; p += (size_t)32 * 2048 * 64 * 2;
    unsigned short* Vts = (unsigned short*)p; p += (size_t)32 * 2048 * 64 * 2;
    unsigned short* Ep  = (unsigned short*)p; p += (size_t)EPAD_ROWS * 64 * 2;

    hipLaunchKernelGGL(prep_kernel, dim3(7776), dim3(256), 0, stream,
                       x, Er, Wq, Wk, Wv, xb, Ep, Wt);
    hipLaunchKernelGGL(qkv_gemm, dim3(768), dim3(256), 0, stream,
                       xb, Wt, bq, bk, bv, Qs, Ks, Vts);
    hipLaunchKernelGGL(attn_kernel, dim3(512), dim3(256), 0, stream, Qs, Ks, Vts, Ep, out);
}

// Round 6
// 176.322 us; speedup vs baseline: 1.2274x; 1.0064x over previous
//
#include <hip/hip_runtime.h>
#include <hip/hip_bf16.h>

#define SLEN   2048
#define DMODEL 1024
#define NHEADS 16
#define DHEAD  64
#define NBATCH 2
#define EPAD_ROWS 2432   // SLEN + 384 zero rows so rel-band/ring never reads OOB

// Q pre-scale folds softmax 1/8 AND log2(e) so scores are in exp2 domain
#define QSCALE 0.18033688011112042f     // 0.125 * log2(e)
#define EXPB   23.083120654223414f      // 16 * log2(e)

typedef __bf16 bf16x8 __attribute__((ext_vector_type(8)));
typedef float  f32x4  __attribute__((ext_vector_type(4)));

__device__ __forceinline__ unsigned short f2bf(float f) {
    unsigned int u = __builtin_bit_cast(unsigned int, f);
    return (unsigned short)((u + 0x7fffu + ((u >> 16) & 1u)) >> 16);  // RNE
}

// bare v_exp_f32 (2^x); args in [-60, 20], flush-to-zero fine
__device__ __forceinline__ float exp2_hw(float x) {
    float r;
    asm("v_exp_f32 %0, %1" : "=v"(r) : "v"(x));
    return r;
}

// pack two f32 -> (bf16 lo, bf16 hi), RNE
__device__ __forceinline__ unsigned int cvtpk_bf16(float lo, float hi) {
    unsigned int d;
    asm("v_cvt_pk_bf16_f32 %0, %1, %2" : "=v"(d) : "v"(lo), "v"(hi));
    return d;
}

__device__ __forceinline__ bf16x8 ld8(const unsigned short* p) {
    union { uint4 u; bf16x8 b; } t;
    t.u = *(const uint4*)p;
    return t.b;
}

// async global->LDS, 16B per lane; lds base must be wave-uniform
__device__ __forceinline__ void glds16(const unsigned short* g, unsigned short* l) {
    __builtin_amdgcn_global_load_lds(
        (const __attribute__((address_space(1))) unsigned int*)g,
        (__attribute__((address_space(3))) unsigned int*)l, 16, 0, 0);
}

// ---------------- merged prep kernel ----------------
__global__ __launch_bounds__(256) void prep_kernel(
    const float* __restrict__ x, const float* __restrict__ Er,
    const float* __restrict__ Wq, const float* __restrict__ Wk,
    const float* __restrict__ Wv,
    unsigned short* __restrict__ xb, unsigned short* __restrict__ Ep,
    unsigned short* __restrict__ Wt) {
    const int bi = blockIdx.x, tid = threadIdx.x;
    if (bi < 4096) {
        int i = (bi * 256 + tid) * 4;
        float4 v = *(const float4*)(x + i);
        ushort4 o;
        o.x = f2bf(v.x); o.y = f2bf(v.y); o.z = f2bf(v.z); o.w = f2bf(v.w);
        *(ushort4*)(xb + i) = o;
    } else if (bi < 4704) {
        int i = (bi - 4096) * 256 + tid;        // 2432*64 elements
        int row = i >> 6;
        unsigned short v = 0;
        if (row < SLEN) v = f2bf(Er[i]);
        Ep[i] = v;
    } else {
        __shared__ float tile[32][33];
        const int b3 = bi - 4704;               // 0..3071
        const int z = b3 >> 10, rem = b3 & 1023;
        const int n0 = (rem & 31) * 32, k0 = (rem >> 5) * 32;
        const float* W = (z == 0) ? Wq : (z == 1 ? Wk : Wv);
        unsigned short* out = Wt + (size_t)z * DMODEL * DMODEL;
        const int tx = tid & 31, ty = tid >> 5;  // (32,8)
        for (int r = 0; r < 32; r += 8)
            tile[ty + r][tx] = W[(size_t)(k0 + ty + r) * DMODEL + n0 + tx];
        __syncthreads();
        for (int r = 0; r < 32; r += 8)
            out[(size_t)(n0 + ty + r) * DMODEL + k0 + tx] = f2bf(tile[tx][ty + r]);
    }
}

// ---------------- QKV projection GEMM (R3 config, unchanged) ----------------
__global__ __launch_bounds__(256, 3) void qkv_gemm(
    const unsigned short* __restrict__ xb, const unsigned short* __restrict__ Wt,
    const float* __restrict__ bq, const float* __restrict__ bk, const float* __restrict__ bv,
    unsigned short* __restrict__ Qs, unsigned short* __restrict__ Ks,
    unsigned short* __restrict__ Vts) {
    const int b = blockIdx.x;
    const int x7 = b & 7, s = b >> 3;
    const int mt = ((x7 >> 1) << 3) | (s & 7);          // 0..31
    const int ntile = ((x7 & 1) << 2) | ((s >> 3) & 3); // 0..7
    const int z = s >> 5;                               // 0..2
    const int m0 = mt * 128, n0 = ntile * 128;

    const float* bias = (z == 0) ? bq : (z == 1 ? bk : bv);
    const unsigned short* Wz = Wt + (size_t)z * DMODEL * DMODEL;

    __shared__ __align__(16) unsigned short As[128][64];
    __shared__ __align__(16) unsigned short Bs[128][64];

    const int tid = threadIdx.x;
    const int wave = tid >> 6, lane = tid & 63, l16 = lane & 15, quad = lane >> 4;
    const int wm = (wave >> 1) * 64, wn = (wave & 1) * 64;

    const int lr8 = lane >> 3;
    const int sc  = ((lane & 7) ^ lr8) * 8;    // swizzled source col (u16)

    f32x4 acc[4][4];
#pragma unroll
    for (int mi = 0; mi < 4; mi++)
#pragma unroll
        for (int ni = 0; ni < 4; ni++) acc[mi][ni] = (f32x4){0.f, 0.f, 0.f, 0.f};

    for (int j = 0; j < 16; ++j) {
        if (j) __syncthreads();                // readers of tile j-1 done
        const int k0 = j * 64;
#pragma unroll
        for (int c = 0; c < 4; c++) {
            const int seg = wave * 4 + c;
            const int r8  = seg * 8 + lr8;
            glds16(&xb[(size_t)(m0 + r8) * DMODEL + k0 + sc], &As[seg * 8][0]);
            glds16(&Wz[(size_t)(n0 + r8) * DMODEL + k0 + sc], &Bs[seg * 8][0]);
        }
        __syncthreads();                       // stage landed (vmcnt drained)

        const unsigned short (*Aarr)[64] = (z == 2) ? Bs : As;
        const unsigned short (*Barr)[64] = (z == 2) ? As : Bs;
#pragma unroll
        for (int ks = 0; ks < 2; ks++) {
            const int pc = ((ks * 4 + quad) ^ (l16 & 7)) * 8;
            bf16x8 a[4], bb[4];
#pragma unroll
            for (int mi = 0; mi < 4; mi++) a[mi] = ld8(&Aarr[wm + mi * 16 + l16][pc]);
#pragma unroll
            for (int ni = 0; ni < 4; ni++) bb[ni] = ld8(&Barr[wn + ni * 16 + l16][pc]);
#pragma unroll
            for (int mi = 0; mi < 4; mi++)
#pragma unroll
                for (int ni = 0; ni < 4; ni++)
                    acc[mi][ni] = __builtin_amdgcn_mfma_f32_16x16x32_bf16(a[mi], bb[ni], acc[mi][ni], 0, 0, 0);
        }
    }

    if (z == 2) {
#pragma unroll
        for (int mi = 0; mi < 4; mi++)
#pragma unroll
            for (int r = 0; r < 4; r++) {
                const int n = n0 + wm + mi * 16 + quad * 4 + r;
                const float bb = bias[n];
                const int h = n >> 6, d = n & 63;
#pragma unroll
                for (int ni = 0; ni < 4; ni++) {
                    const int m = m0 + wn + ni * 16 + l16;
                    const int bi = m >> 11, ss = m & 2047;
                    Vts[((size_t)((bi * NHEADS + h) * 64 + d)) * SLEN + ss] = f2bf(acc[mi][ni][r] + bb);
                }
            }
    } else {
#pragma unroll
        for (int ni = 0; ni < 4; ni++) {
            const int n = n0 + wn + ni * 16 + l16;
            const float bb = bias[n];
            const int h = n >> 6, d = n & 63;
#pragma unroll
            for (int mi = 0; mi < 4; mi++)
#pragma unroll
                for (int r = 0; r < 4; r++) {
                    const int m = m0 + wm + mi * 16 + quad * 4 + r;
                    const int bi = m >> 11, ss = m & 2047;
                    float v = acc[mi][ni][r] + bb;
                    if (z == 0)
                        Qs[((size_t)(bi * NHEADS + h) * SLEN + ss) * 64 + d] = f2bf(v * QSCALE);
                    else
                        Ks[((size_t)(bi * NHEADS + h) * SLEN + ss) * 64 + d] = f2bf(v);
                }
        }
    }
}

// ---------------- cooperative flash attention — SWAPPED-OPERAND (R5) --------
// R4 structure with the skew-gather sender/receiver fix: hiE (which accE
// group a lane SENDS) must be evaluated for the RECEIVER it serves --
// quad_v = (quad - ((r+15-l16)>>2)) & 3 -- not the sender's own quad.
// R4 used the sender's quad: wrong group whenever the gather carried across
// a quad boundary (absmax 2.98). permE (receiver side) was already correct.
__global__ __launch_bounds__(256, 2) void attn_kernel(
    const unsigned short* __restrict__ Q,   // (BH,S,64), pre-scaled by QSCALE
    const unsigned short* __restrict__ K,   // (BH,S,64)
    const unsigned short* __restrict__ Vt,  // (BH,64,S)
    const unsigned short* __restrict__ Ep,  // (EPAD_ROWS,64)
    float* __restrict__ out) {              // (B,S,DMODEL)
    const int tid = threadIdx.x;
    const int wave = tid >> 6, lane = tid & 63, l16 = lane & 15, quad = lane >> 4;
    const int lr8 = lane >> 3;
    const int swz = ((lane & 7) ^ lr8) * 8;   // swizzled source chunk (u16)

    const int bh = blockIdx.x & 31;
    const int pg = blockIdx.x >> 5;            // 0..15

    __shared__ __align__(16) unsigned short Ksh[2][64 * 64];  // K tile  [t][d], dbuf
    __shared__ __align__(16) unsigned short Vsh[2][64 * 64];  // V^T tile[d][t], dbuf
    __shared__ __align__(16) unsigned short Esh[256 * 64];    // Er ring (4 panels)

    const unsigned short* Qb = Q + (size_t)bh * SLEN * 64;
    const unsigned short* Kb = K + (size_t)bh * SLEN * 64;
    const unsigned short* Vb = Vt + (size_t)bh * 64 * SLEN;
    const int ob = bh >> 4, oh = bh & 15;

    // hoisted loop-invariant lane math
    const int pc0 = (quad ^ (l16 & 7)) * 8;          // de-swizzle, k-chunk 0
    const int pc1 = ((4 + quad) ^ (l16 & 7)) * 8;    // de-swizzle, k-chunk 1
    // skew gather (swapped layout): receiver (quad,l16) output (nt,r) needs
    // band offset o = nt*16 + idx_v, idx_v = quad*4 + r + 15 - l16, served by
    // lane (quad_s = (idx_v&15)>>2, l16) register (nt + (idx_v>=16))[idx_v&3].
    // permE: receiver-side pull index. hiE: SENDER-side group select -- must
    // use the receiver's idx_v, reconstructed from the sender's own coords.
    const int krot = (15 - l16) & 3;
    const bool c1 = (krot & 1) != 0, c2 = (krot & 2) != 0;
    int permE[4]; bool hiE[4];
#pragma unroll
    for (int r = 0; r < 4; r++) {
        const int idx = quad * 4 + r + 15 - l16;     // receiver-side idx_v: 0..30
        permE[r] = ((idx >> 2) & 3) * 16 + l16;      // sender lane to pull from
        const int c  = r + 15 - l16;                 // sender-side: 0..18
        const int qv = (quad - (c >> 2)) & 3;        // quad of receiver I serve
        hiE[r] = (qv * 4 + c) >= 16;                 // that receiver's idx_v>=16
    }

    int s0 = pg * 64;
    int ntp = pg + 1;

#pragma unroll 1
    for (int pass = 0; pass < 2; ++pass) {
        const int sw = s0 + 16 * wave;          // this wave's 16 q-rows
        const bf16x8 aq0 = ld8(Qb + (size_t)(sw + l16) * 64 + quad * 8);
        const bf16x8 aq1 = ld8(Qb + (size_t)(sw + l16) * 64 + 32 + quad * 8);

        f32x4 accO[4];                          // O^T: d = ntd*16+quad*4+r, q=l16
        float sacc[4];
#pragma unroll
        for (int nt = 0; nt < 4; nt++) accO[nt] = (f32x4){0.f, 0.f, 0.f, 0.f};
#pragma unroll
        for (int r = 0; r < 4; r++) sacc[r] = 0.f;

        const int p0row = SLEN - 64 - s0;       // Er panel base at t0=0 (mult of 64)

        // ---- prologue: K/V (t0=0) into buf0 + Er panels ----
#pragma unroll
        for (int c = 0; c < 2; c++) {
            const int seg = wave * 2 + c;
            glds16(&Kb[(size_t)(seg * 8 + lr8) * 64 + swz], &Ksh[0][seg * 8 * 64]);
            glds16(&Vb[(size_t)(seg * 8 + lr8) * SLEN + swz], &Vsh[0][seg * 8 * 64]);
        }
#pragma unroll
        for (int u = 0; u < 6; u++) {
            const int idx = wave * 6 + u;       // 24 segs = 3 panels (192 rows)
            const int grow = p0row + idx * 8;
            glds16(&Ep[(size_t)(grow + lr8) * 64 + swz], &Esh[(grow & 255) * 64]);
        }
        __syncthreads();

        for (int j = 0; j < ntp; ++j) {
            const int t0 = j * 64;
            const int cur = j & 1;

            // ---- prefetch next tile ----
            if (j + 1 < ntp) {
                const int t1 = t0 + 64, nb = cur ^ 1;
#pragma unroll
                for (int c = 0; c < 2; c++) {
                    const int seg = wave * 2 + c;
                    glds16(&Kb[(size_t)(t1 + seg * 8 + lr8) * 64 + swz], &Ksh[nb][seg * 8 * 64]);
                    glds16(&Vb[(size_t)(seg * 8 + lr8) * SLEN + t1 + swz], &Vsh[nb][seg * 8 * 64]);
                }
                const int er = p0row + t0 + 128;  // panel needed at iter j+1
#pragma unroll
                for (int c = 0; c < 2; c++) {
                    const int seg = wave * 2 + c;
                    glds16(&Ep[(size_t)(er + seg * 8 + lr8) * 64 + swz],
                           &Esh[((er + seg * 8) & 255) * 64]);
                }
            }

            // ---- QK^T swapped: S^T[t][q], t = nt*16+quad*4+r, q = l16 ----
            f32x4 accS[4];
#pragma unroll
            for (int nt = 0; nt < 4; nt++)
                accS[nt] = (f32x4){-EXPB, -EXPB, -EXPB, -EXPB};
#pragma unroll
            for (int nt = 0; nt < 4; nt++) {
                bf16x8 bk0 = ld8(&Ksh[cur][(nt * 16 + l16) * 64 + pc0]);
                bf16x8 bk1 = ld8(&Ksh[cur][(nt * 16 + l16) * 64 + pc1]);
                accS[nt] = __builtin_amdgcn_mfma_f32_16x16x32_bf16(bk0, aq0, accS[nt], 0, 0, 0);
                accS[nt] = __builtin_amdgcn_mfma_f32_16x16x32_bf16(bk1, aq1, accS[nt], 0, 0, 0);
            }

            // ---- rel band swapped: E^T[band row][q] ----
            const int rm0 = (SLEN - 16 - sw + t0) & 255;
            f32x4 accE[5];
#pragma unroll
            for (int nt = 0; nt < 5; nt++) accE[nt] = (f32x4){0.f, 0.f, 0.f, 0.f};
#pragma unroll
            for (int nt = 0; nt < 5; nt++) {
                const int rowm = (rm0 + nt * 16 + l16) & 255;
                bf16x8 be0 = ld8(&Esh[rowm * 64 + pc0]);
                bf16x8 be1 = ld8(&Esh[rowm * 64 + pc1]);
                accE[nt] = __builtin_amdgcn_mfma_f32_16x16x32_bf16(be0, aq0, accE[nt], 0, 0, 0);
                accE[nt] = __builtin_amdgcn_mfma_f32_16x16x32_bf16(be1, aq1, accE[nt], 0, 0, 0);
            }

            // ---- per-lane register rotation of accE groups by krot ----
            // sender must provide element (r + 15 - l16) & 3 at slot r
            f32x4 rotE[5];
#pragma unroll
            for (int g = 0; g < 5; g++) {
                f32x4 A = accE[g], t, rt;
#pragma unroll
                for (int r = 0; r < 4; r++) t[r] = c1 ? A[(r + 1) & 3] : A[r];
#pragma unroll
                for (int r = 0; r < 4; r++) rt[r] = c2 ? t[(r + 2) & 3] : t[r];
                rotE[g] = rt;
            }

            // ---- skew gather + exp2 (mask only on diagonal tile) ----
            float pe[4][4];
            auto scoreblk = [&](bool masked) {
#pragma unroll
                for (int nt = 0; nt < 4; nt++) {
#pragma unroll
                    for (int r = 0; r < 4; r++) {
                        float send = hiE[r] ? rotE[nt + 1][r] : rotE[nt][r];
                        float rel = __shfl(send, permE[r]);
                        float p = exp2_hw(accS[nt][r] + rel);
                        if (masked)
                            p = (t0 + nt * 16 + quad * 4 + r <= sw + l16) ? p : 0.0f;
                        sacc[r] += p;
                        pe[nt][r] = p;
                    }
                }
            };
            if (t0 + 63 <= sw) scoreblk(false);   // fully-unmasked tile
            else               scoreblk(true);    // diagonal tile

            // ---- P^T -> bf16 B-frags, in-register (cvt_pk + permlane) ----
            // w[nt][rr] = bf16 pair (t, t+1), t = nt*16 + quad*4 + 2rr
            unsigned int w[4][2];
#pragma unroll
            for (int nt = 0; nt < 4; nt++) {
                w[nt][0] = cvtpk_bf16(pe[nt][0], pe[nt][1]);
                w[nt][1] = cvtpk_bf16(pe[nt][2], pe[nt][3]);
            }
            // chunk c covers t-local [32c,32c+32). With A=w[2c][rr], B=w[2c+1][rr]:
            // pl32(A,B) then pl16(A,B) -> A = [A.r0,A.r2,B.r0,B.r2] (frag word
            // 2rr even-k pair), B = [A.r1,A.r3,B.r1,B.r3] (frag word 2rr+1).
            // Frag word order per lane: (X0, X1, Y0, Y1) = k pairs quad*8+{0,2,4,6}.
            bf16x8 pf[2];
#pragma unroll
            for (int c = 0; c < 2; c++) {
                unsigned int a0 = w[2 * c][0], b0 = w[2 * c + 1][0];
                unsigned int a1 = w[2 * c][1], b1 = w[2 * c + 1][1];
                asm volatile("v_permlane32_swap_b32 %0, %1" : "+v"(a0), "+v"(b0));
                asm volatile("v_permlane16_swap_b32 %0, %1" : "+v"(a0), "+v"(b0));
                asm volatile("v_permlane32_swap_b32 %0, %1" : "+v"(a1), "+v"(b1));
                asm volatile("v_permlane16_swap_b32 %0, %1" : "+v"(a1), "+v"(b1));
                union { uint4 u; bf16x8 b; } t;
                t.u = (uint4){a0, a1, b0, b1};
                pf[c] = t.b;
            }

            // ---- PV swapped: O^T += V^T x P^T ----
#pragma unroll
            for (int ntd = 0; ntd < 4; ntd++) {
                bf16x8 bv0 = ld8(&Vsh[cur][(ntd * 16 + l16) * 64 + pc0]);
                bf16x8 bv1 = ld8(&Vsh[cur][(ntd * 16 + l16) * 64 + pc1]);
                accO[ntd] = __builtin_amdgcn_mfma_f32_16x16x32_bf16(bv0, pf[0], accO[ntd], 0, 0, 0);
                accO[ntd] = __builtin_amdgcn_mfma_f32_16x16x32_bf16(bv1, pf[1], accO[ntd], 0, 0, 0);
            }

            __syncthreads();   // staged j+1 landed; compute j done before overwrite
        }

        // ---- pass epilogue: cross-quad denom reduce + normalize + store ----
        float s4 = (sacc[0] + sacc[1]) + (sacc[2] + sacc[3]);
        s4 += __shfl_xor(s4, 16);
        s4 += __shfl_xor(s4, 32);
        const float inv = 1.f / s4;
        const int srow = sw + l16;
        float* orow = out + ((size_t)(ob * SLEN + srow)) * DMODEL + oh * 64 + quad * 4;
#pragma unroll
        for (int ntd = 0; ntd < 4; ntd++) {
            float4 st = {accO[ntd][0] * inv, accO[ntd][1] * inv,
                         accO[ntd][2] * inv, accO[ntd][3] * inv};
            *(float4*)(orow + ntd * 16) = st;
        }

        // switch to pass B: q-tile 31-pg
        s0 = (31 - pg) * 64;
        ntp = 32 - pg;
    }
}

// ---------------- host launcher ----------------
extern "C" void kernel_launch(void* const* d_in, const int* in_sizes, int n_in,
                              void* d_out, int out_size, void* d_ws, size_t ws_size,
                              hipStream_t stream) {
    const float* x  = (const float*)d_in[0];
    const float* Wq = (const float*)d_in[1];
    const float* bq = (const float*)d_in[2];
    const float* Wk = (const float*)d_in[3];
    const float* bk = (const float*)d_in[4];
    const float* Wv = (const float*)d_in[5];
    const float* bv = (const float*)d_in[6];
    const float* Er = (const float*)d_in[7];
    float* out = (float*)d_out;

    // workspace carve (~38.4 MB total)
    char* p = (char*)d_ws;
    unsigned short* xb  = (unsigned short*)p; p += (size_t)4096 * 1024 * 2;
    unsigned short* Wt  = (unsigned short*)p; p += (size_t)3 * 1024 * 1024 * 2;
    unsigned short* Qs  = (unsigned short*)p; p += (size_t)32 * 2048 * 64 * 2;
    unsigned short* Ks  = (unsigned short*)p; p += (size_t)32 * 2048 * 64 * 2;
    unsigned short* Vts = (unsigned short*)p; p += (size_t)32 * 2048 * 64 * 2;
    unsigned short* Ep  = (unsigned short*)p; p += (size_t)EPAD_ROWS * 64 * 2;

    hipLaunchKernelGGL(prep_kernel, dim3(7776), dim3(256), 0, stream,
                       x, Er, Wq, Wk, Wv, xb, Ep, Wt);
    hipLaunchKernelGGL(qkv_gemm, dim3(768), dim3(256), 0, stream,
                       xb, Wt, bq, bk, bv, Qs, Ks, Vts);
    hipLaunchKernelGGL(attn_kernel, dim3(512), dim3(256), 0, stream, Qs, Ks, Vts, Ep, out);
}